// Round 8
// baseline (269.832 us; speedup 1.0000x reference)
//
#include <hip/hip_runtime.h>
#include <math.h>

#define B_DIM 8
#define T_DIM 512
#define H_DIM 768
#define NTOK 511       // T - 1
#define NLAY 9         // 13 - LAYER_START
#define LAYER_START 4
#define NBAND 35       // pairs with |i-j| <= 4 (all that's needed)

// banded Gram index: pair (lo, lo+d), d<=4 -> BOFF(d)+lo
#define BOFF(d) ((d)*9 - (d) * ((d)-1) / 2)

// Inter-kernel buffers. Module globals (never touch d_ws). Every element read
// by fin_k is written by wk_main in the same call -> poison-safe, graph-safe.
__device__ float g_part[B_DIM * NTOK * H_DIM];  // per-token weighted vector, 12.6 MB
__device__ float g_var[B_DIM * NTOK];           // var_tok, 16 KB

// ---- DPP cross-lane (VALU pipe, no DS) ----
template <int CTRL>
__device__ __forceinline__ float dpp_mov(float x) {
  return __builtin_bit_cast(
      float, __builtin_amdgcn_update_dpp(0, __builtin_bit_cast(int, x), CTRL,
                                         0xF, 0xF, true));
}
// 64-lane sum; total lands in lane 63.
__device__ __forceinline__ float wave_sum_dpp(float x) {
  x += dpp_mov<0x111>(x);  // row_shr:1
  x += dpp_mov<0x112>(x);  // row_shr:2
  x += dpp_mov<0x114>(x);  // row_shr:4
  x += dpp_mov<0x118>(x);  // row_shr:8
  x += dpp_mov<0x142>(x);  // row_bcast:15
  x += dpp_mov<0x143>(x);  // row_bcast:31
  return x;
}

// ===================== main: one token per 3-wave block =====================
// grid (NTOK, B_DIM) x 192 threads. Wave w owns H[w*256 .. w*256+256):
// v = 9 x float4 = 36 VGPRs -> live set ~95, fits 128-VGPR cap (192,4), no
// spill. Input read exactly once; v stays in registers through the epilogue.
__global__ __launch_bounds__(192, 4) void wk_main(const float* __restrict__ ahs) {
  const int t = blockIdx.x;   // 0..510
  const int b = blockIdx.y;   // 0..7
  const int w = threadIdx.x >> 6;   // 0..2 : H-segment
  const int lane = threadIdx.x & 63;

  __shared__ float sG[3][NBAND];   // per-wave partial Gram
  __shared__ float sGc[NBAND + 1]; // combined Gram
  __shared__ float sC[NLAY + 1];   // epilogue weights c[l]

  const size_t LSTR = (size_t)B_DIM * T_DIM * H_DIM;
  const float* base = ahs + (size_t)LAYER_START * LSTR +
                      ((size_t)b * T_DIM + t) * H_DIM + w * 256 + lane * 4;

  // ---- load 9 layers x 1 float4 per lane (this wave's 256-column slice) ----
  float4 v[NLAY];
#pragma unroll
  for (int l = 0; l < NLAY; ++l)
    v[l] = *reinterpret_cast<const float4*>(base + (size_t)l * LSTR);

  // ---- banded partial Gram over this lane's 4 columns ----
  float g[NBAND];
#pragma unroll
  for (int d = 0; d <= 4; ++d) {
#pragma unroll
    for (int i = 0; i + d < NLAY; ++i) {
      const float4 x = v[i], y = v[i + d];
      g[BOFF(d) + i] = x.x * y.x + x.y * y.y + x.z * y.z + x.w * y.w;
    }
  }

  // ---- DPP wave reduction; totals land in lane 63 ----
#pragma unroll
  for (int p = 0; p < NBAND; ++p) g[p] = wave_sum_dpp(g[p]);

  if (lane == 63) {
#pragma unroll
    for (int p = 0; p < NBAND; ++p) sG[w][p] = g[p];
  }
  __syncthreads();

  // ---- combine 3 partial Grams (threads 0..34 = wave 0 lanes) ----
  if (threadIdx.x < NBAND)
    sGc[threadIdx.x] =
        sG[0][threadIdx.x] + sG[1][threadIdx.x] + sG[2][threadIdx.x];
  __syncthreads();

  // ---- tail on wave 0 only: per-lane-k Cholesky (R == QR's R up to row
  //      signs, which cancel in align/novelty) ----
  if (w == 0) {
    const int k = lane < NLAY ? lane : NLAY - 1;
    const int nl = (k >= 2) ? 2 : 0;
    const int nrr = (NLAY - 1 - k) < 2 ? (NLAY - 1 - k) : 2;
    const int m = nl + nrr + 1;  // 3..5, self row last

    auto rowf = [&](int i) -> int {
      return (i < nl) ? (k - 2 + i) : ((i < nl + nrr) ? (k + 1 + i - nl) : k);
    };
    auto GK = [&](int i, int j) -> float {
      int a = rowf(i), c = rowf(j);
      int lo = a < c ? a : c;
      int d = (a < c ? c : a) - lo;  // 0..4 (window span <= 4)
      return sGc[d * 9 - d * (d - 1) / 2 + lo];
    };

    float R[5][5];
#pragma unroll
    for (int j = 0; j < 5; ++j)
#pragma unroll
      for (int i = 0; i < 5; ++i) R[i][j] = 0.f;

#pragma unroll
    for (int j = 0; j < 5; ++j) {
      if (j < m) {
#pragma unroll
        for (int i = 0; i < 5; ++i) {
          if (i < j) {
            float s = GK(i, j);
#pragma unroll
            for (int p = 0; p < 4; ++p)
              if (p < i) s -= R[p][i] * R[p][j];
            R[i][j] = s / R[i][i];
          }
        }
        float sjj = GK(j, j);
#pragma unroll
        for (int p = 0; p < 4; ++p)
          if (p < j) sjj -= R[p][j] * R[p][j];
        R[j][j] = sqrtf(fmaxf(sjj, 0.f));
      }
    }

    float r[5];
#pragma unroll
    for (int i = 0; i < 5; ++i)
      r[i] = (m == 3) ? R[i][2] : ((m == 4) ? R[i][3] : R[i][4]);

    float rowmean[4] = {0.f, 0.f, 0.f, 0.f};
#pragma unroll
    for (int j = 0; j < 4; ++j) {
      if (j < m - 1) {
        float cn = 0.f;
#pragma unroll
        for (int i = 0; i < 4; ++i)
          if (i <= j) cn += R[i][j] * R[i][j];
        cn = fmaxf(sqrtf(cn), 1e-12f);
        const float inv = 1.f / cn;
#pragma unroll
        for (int i = 0; i < 4; ++i)
          if (i < m - 1) rowmean[i] += R[i][j] * inv;
      }
    }

    const float inv_m1 = 1.f / (float)(m - 1);
    float dotv = 0.f, nrm2 = 0.f;
#pragma unroll
    for (int i = 0; i < 4; ++i) {
      if (i < m - 1) {
        dotv += (rowmean[i] * inv_m1) * r[i];
        nrm2 += r[i] * r[i];
      }
    }
    const float align_raw = dotv / sqrtf(nrm2);
    const float align_v = 1.f / (align_raw * (float)m * 2.f);
    const float rlast = (m == 3) ? r[2] : ((m == 4) ? r[3] : r[4]);
    const float nov_v = fabsf(rlast) / sqrtf(nrm2 + rlast * rlast);

    // gather the 9 (align, nov) from lanes 0..8
    float al[NLAY], nv[NLAY];
    float asum = 0.f, nsum = 0.f;
#pragma unroll
    for (int l = 0; l < NLAY; ++l) {
      al[l] = __shfl(align_v, l, 64);
      nv[l] = __shfl(nov_v, l, 64);
      asum += al[l];
      nsum += nv[l];
    }
    float alpha[NLAY];
    float csum = 0.f;
#pragma unroll
    for (int l = 0; l < NLAY; ++l) {
      alpha[l] = al[l] / asum + nv[l] / nsum;
      csum += alpha[l];
    }
    const float inv_csum = 1.f / csum;

    // adjacent-layer cosine sims -> sample variance (ddof=1)
    float sims[NLAY - 1];
    float smean = 0.f;
#pragma unroll
    for (int j = 0; j < NLAY - 1; ++j) {
      const float num = sGc[BOFF(1) + j];
      const float den = fmaxf(sqrtf(sGc[j]) * sqrtf(sGc[j + 1]), 1e-8f);
      sims[j] = num / den;
      smean += sims[j];
    }
    smean *= (1.f / 8.f);
    float var = 0.f;
#pragma unroll
    for (int j = 0; j < NLAY - 1; ++j) {
      const float d = sims[j] - smean;
      var += d * d;
    }
    var *= (1.f / 7.f);

    if (lane < NLAY) sC[lane] = var * alpha[lane] * inv_csum;
    if (lane == 0) g_var[b * NTOK + t] = var;
  }
  __syncthreads();

  // ---- epilogue: every wave scales its own register-resident slice ----
  float c[NLAY];
#pragma unroll
  for (int l = 0; l < NLAY; ++l) c[l] = sC[l];

  float4 o;
  o.x = 0.f; o.y = 0.f; o.z = 0.f; o.w = 0.f;
#pragma unroll
  for (int l = 0; l < NLAY; ++l) {
    o.x += c[l] * v[l].x;
    o.y += c[l] * v[l].y;
    o.z += c[l] * v[l].z;
    o.w += c[l] * v[l].w;
  }
  *reinterpret_cast<float4*>(g_part + ((size_t)(b * NTOK + t)) * H_DIM +
                             w * 256 + lane * 4) = o;
}

// ===================== fin: reduce tokens + normalize =====================
__global__ __launch_bounds__(256) void fin_k(float* __restrict__ out) {
  const int b = blockIdx.y;
  const int h = blockIdx.x * 256 + threadIdx.x;

  float acc = 0.f;
#pragma unroll 8
  for (int t = 0; t < NTOK; ++t)
    acc += g_part[((size_t)(b * NTOK + t)) * H_DIM + h];

  float sv = 0.f;  // uniform address stream -> scalar loads
#pragma unroll 8
  for (int t = 0; t < NTOK; ++t) sv += g_var[b * NTOK + t];

  out[b * H_DIM + h] = acc / sv;
}

extern "C" void kernel_launch(void* const* d_in, const int* in_sizes, int n_in,
                              void* d_out, int out_size, void* d_ws, size_t ws_size,
                              hipStream_t stream) {
  const float* ahs = (const float*)d_in[0];
  // d_in[1] = attention_mask: unused by the reference computation
  float* out = (float*)d_out;
  (void)d_ws; (void)ws_size;

  wk_main<<<dim3(NTOK, B_DIM), dim3(192), 0, stream>>>(ahs);
  fin_k<<<dim3(3, B_DIM), dim3(256), 0, stream>>>(out);
}